// Round 6
// baseline (266.145 us; speedup 1.0000x reference)
//
#include <hip/hip_runtime.h>
#include <hip/hip_fp16.h>

#define NN 50000
#define NPAD 50048
#define NE 800000
#define D 128
#define BPAD 136
#define APAD 136

typedef __attribute__((ext_vector_type(8))) short bf16x8;
typedef __attribute__((ext_vector_type(4))) float f32x4;

__device__ inline unsigned short f2bf(float f) {
    unsigned int b = __float_as_uint(f);
    return (unsigned short)((b + 0x7FFFu + ((b >> 16) & 1u)) >> 16);
}
__device__ inline float bf2f(unsigned short u) {
    return __uint_as_float(((unsigned int)u) << 16);
}

// ---------------- CSR build ----------------

__global__ void k_degree(const int* __restrict__ dst, int* __restrict__ cnt,
                         int* __restrict__ rank) {
    int e = blockIdx.x * 256 + threadIdx.x;
    if (e < NE) {
        int d = dst[e];
        rank[e] = atomicAdd(&cnt[d], 1);
    }
}

__global__ void k_scan_block(const int* __restrict__ cnt, int* __restrict__ excl,
                             int* __restrict__ bsum) {
    __shared__ int sm[256];
    int t = threadIdx.x;
    int idx = blockIdx.x * 256 + t;
    int v = (idx < NN) ? cnt[idx] : 0;
    sm[t] = v;
    __syncthreads();
    for (int o = 1; o < 256; o <<= 1) {
        int u = (t >= o) ? sm[t - o] : 0;
        __syncthreads();
        sm[t] += u;
        __syncthreads();
    }
    if (idx < NN) excl[idx] = sm[t] - v;
    if (t == 255) bsum[blockIdx.x] = sm[255];
}

__global__ void k_scan_top(const int* __restrict__ bsum, int* __restrict__ boff) {
    __shared__ int sm[256];
    const int NB = (NN + 255) / 256;
    int t = threadIdx.x;
    int v = (t < NB) ? bsum[t] : 0;
    sm[t] = v;
    __syncthreads();
    for (int o = 1; o < 256; o <<= 1) {
        int u = (t >= o) ? sm[t - o] : 0;
        __syncthreads();
        sm[t] += u;
        __syncthreads();
    }
    if (t < NB) boff[t] = sm[t] - v;
}

__global__ void k_scan_add(int* __restrict__ rowptr, const int* __restrict__ boff,
                           const int* __restrict__ cnt, float* __restrict__ dinv) {
    int idx = blockIdx.x * 256 + threadIdx.x;
    if (idx < NN) {
        rowptr[idx] += boff[idx >> 8];
        dinv[idx] = rsqrtf((float)(cnt[idx] + 1));
    } else if (idx == NN) {
        rowptr[NN] = NE;
    }
}

__global__ void k_fill(const int* __restrict__ src, const int* __restrict__ dst,
                       const int* __restrict__ rowptr, const int* __restrict__ rank,
                       int* __restrict__ col) {
    int e = blockIdx.x * 256 + threadIdx.x;
    if (e < NE) {
        int d = dst[e];
        int pos = rowptr[d] + rank[e];
        __builtin_nontemporal_store(src[e], &col[pos]);
    }
}

// ---------------- prep: W split-bf16 (transposed), all 3 ----------------

__global__ void k_convW3(const float* __restrict__ W0, const float* __restrict__ W1,
                         const float* __restrict__ W2, unsigned short* __restrict__ Wh,
                         unsigned short* __restrict__ Wl) {
    int i = blockIdx.x * 256 + threadIdx.x;
    if (i >= 3 * D * D) return;
    int m = i / (D * D), r = i - m * (D * D);
    const float* W = (m == 0) ? W0 : ((m == 1) ? W1 : W2);
    int k = r >> 7, c = r & 127;
    float v = W[r];
    unsigned short h = f2bf(v);
    unsigned short l = f2bf(v - bf2f(h));
    Wh[(size_t)m * D * D + c * D + k] = h;
    Wl[(size_t)m * D * D + c * D + k] = l;
}

// ---------------- GEMM epilogue ----------------

__device__ inline void gemm_store(f32x4 acc[2][4], const float* __restrict__ dinv,
                                  __half* __restrict__ C, int R0, int C0, int lr, int lg) {
    #pragma unroll
    for (int fr = 0; fr < 2; fr++) {
        int rb = R0 + fr * 16 + lg * 4;
        #pragma unroll
        for (int j = 0; j < 4; j++) {
            int r = rb + j;
            if (r < NN) {
                float s = dinv[r];
                #pragma unroll
                for (int fc = 0; fc < 4; fc++)
                    C[(size_t)r * D + C0 + fc * 16 + lr] =
                        __float2half_rn(acc[fr][fc][j] * s);
            }
        }
    }
}

// ---------------- layer 0 GEMM: fp32 X, split in-register ----------------

__global__ __launch_bounds__(256, 2) void k_gemm_mfma_x(
        const float* __restrict__ X,
        const unsigned short* __restrict__ BhT, const unsigned short* __restrict__ BlT,
        const float* __restrict__ dinv, __half* __restrict__ C) {
    __shared__ short Bs_h[D * BPAD];
    int t = threadIdx.x;
    {
        int c = t >> 1;
        int k0 = (t & 1) * 64;
        const unsigned short* gh = BhT + c * D + k0;
        short* dh = Bs_h + c * BPAD + k0;
        #pragma unroll
        for (int i = 0; i < 8; i++)
            *(int4*)(dh + i * 8) = *(const int4*)(gh + i * 8);
    }
    __syncthreads();

    int w = t >> 6, ln = t & 63;
    int wr = w >> 1, wc = w & 1;
    int R0 = blockIdx.x * 64 + wr * 32;
    int C0 = wc * 64;
    int lr = ln & 15, lg = ln >> 4;

    f32x4 acc[2][4];
    #pragma unroll
    for (int a = 0; a < 2; a++)
        #pragma unroll
        for (int b = 0; b < 4; b++)
            acc[a][b] = (f32x4){0.f, 0.f, 0.f, 0.f};

    const float* Ab = X + (size_t)(R0 + lr) * D + lg * 8;

    #pragma unroll
    for (int ks = 0; ks < 4; ks++) {
        int ko = ks * 32;
        bf16x8 fa_h[2], fa_l[2], fb_h[4], fb_l[4];
        #pragma unroll
        for (int fr = 0; fr < 2; fr++) {
            float4 p0 = *(const float4*)(Ab + fr * 16 * D + ko);
            float4 p1 = *(const float4*)(Ab + fr * 16 * D + ko + 4);
            float vv[8] = {p0.x, p0.y, p0.z, p0.w, p1.x, p1.y, p1.z, p1.w};
            #pragma unroll
            for (int j = 0; j < 8; j++) {
                unsigned short h = f2bf(vv[j]);
                fa_h[fr][j] = (short)h;
                fa_l[fr][j] = (short)f2bf(vv[j] - bf2f(h));
            }
        }
        #pragma unroll
        for (int fc = 0; fc < 4; fc++) {
            int ccol = C0 + fc * 16 + lr;
            fb_h[fc] = *(const bf16x8*)(Bs_h + ccol * BPAD + ko + lg * 8);
            fb_l[fc] = *(const bf16x8*)(BlT + (size_t)ccol * D + ko + lg * 8);
        }
        #pragma unroll
        for (int fr = 0; fr < 2; fr++) {
            #pragma unroll
            for (int fc = 0; fc < 4; fc++) {
                acc[fr][fc] = __builtin_amdgcn_mfma_f32_16x16x32_bf16(
                    fa_h[fr], fb_h[fc], acc[fr][fc], 0, 0, 0);
                acc[fr][fc] = __builtin_amdgcn_mfma_f32_16x16x32_bf16(
                    fa_l[fr], fb_h[fc], acc[fr][fc], 0, 0, 0);
                acc[fr][fc] = __builtin_amdgcn_mfma_f32_16x16x32_bf16(
                    fa_h[fr], fb_l[fc], acc[fr][fc], 0, 0, 0);
            }
        }
    }
    gemm_store(acc, dinv, C, R0, C0, lr, lg);
}

// ---------------- fused: agg(layer k) -> relu -> GEMM(layer k+1) ----------
// Block = 64 dst rows. Phase 1: 8 groups of 32 lanes aggregate (gather T_in),
// bias+relu, split bf16 h/l into LDS. Phase 2: MFMA GEMM, A from LDS, both W
// halves from global (64 KB, L2-resident). Output T_out = dinv[r]*(h@W), fp16.

__global__ __launch_bounds__(256, 3) void k_agg_gemm(
        const __half* __restrict__ T_in,
        const int* __restrict__ rowptr, const int* __restrict__ col,
        const float* __restrict__ dinv, const float* __restrict__ bias,
        const unsigned short* __restrict__ BhT, const unsigned short* __restrict__ BlT,
        __half* __restrict__ T_out) {
    __shared__ short Ah_s[64 * APAD];
    __shared__ short Al_s[64 * APAD];
    int t = threadIdx.x;
    int base = blockIdx.x * 64;
    int g = t >> 5, sl = t & 31;
    int f = sl * 4;

    float4 bv = *(const float4*)(bias + f);

    for (int j = 0; j < 8; j++) {
        int n = g + j * 8;
        int i = base + n;
        float a0 = 0.f, a1 = 0.f, a2 = 0.f, a3 = 0.f;
        if (i < NN) {
            float di = dinv[i];
            float2 raw = *(const float2*)(T_in + (size_t)i * D + f);
            {
                __half2 x0 = *(__half2*)&raw.x, x1 = *(__half2*)&raw.y;
                float2 q0 = __half22float2(x0), q1 = __half22float2(x1);
                a0 = q0.x; a1 = q0.y; a2 = q1.x; a3 = q1.y;
            }
            int e = rowptr[i], r1 = rowptr[i + 1];
            for (; e + 8 <= r1; e += 8) {
                float2 rv[8];
                #pragma unroll
                for (int u = 0; u < 8; u++) {
                    int s = col[e + u];
                    rv[u] = *(const float2*)(T_in + (size_t)s * D + f);
                }
                #pragma unroll
                for (int u = 0; u < 8; u++) {
                    __half2 x0 = *(__half2*)&rv[u].x, x1 = *(__half2*)&rv[u].y;
                    float2 q0 = __half22float2(x0), q1 = __half22float2(x1);
                    a0 += q0.x; a1 += q0.y; a2 += q1.x; a3 += q1.y;
                }
            }
            for (; e < r1; e++) {
                int s = col[e];
                float2 rv = *(const float2*)(T_in + (size_t)s * D + f);
                __half2 x0 = *(__half2*)&rv.x, x1 = *(__half2*)&rv.y;
                float2 q0 = __half22float2(x0), q1 = __half22float2(x1);
                a0 += q0.x; a1 += q0.y; a2 += q1.x; a3 += q1.y;
            }
            a0 = fmaxf(a0 * di + bv.x, 0.f);
            a1 = fmaxf(a1 * di + bv.y, 0.f);
            a2 = fmaxf(a2 * di + bv.z, 0.f);
            a3 = fmaxf(a3 * di + bv.w, 0.f);
        }
        unsigned short h0 = f2bf(a0), h1 = f2bf(a1), h2 = f2bf(a2), h3 = f2bf(a3);
        unsigned short l0 = f2bf(a0 - bf2f(h0)), l1 = f2bf(a1 - bf2f(h1));
        unsigned short l2 = f2bf(a2 - bf2f(h2)), l3 = f2bf(a3 - bf2f(h3));
        *(uint2*)(Ah_s + n * APAD + f) = make_uint2(
            (unsigned)h0 | ((unsigned)h1 << 16), (unsigned)h2 | ((unsigned)h3 << 16));
        *(uint2*)(Al_s + n * APAD + f) = make_uint2(
            (unsigned)l0 | ((unsigned)l1 << 16), (unsigned)l2 | ((unsigned)l3 << 16));
    }
    __syncthreads();

    // phase 2: GEMM
    int w = t >> 6, ln = t & 63;
    int wr = w >> 1, wc = w & 1;
    int R0 = base + wr * 32;
    int C0 = wc * 64;
    int lr = ln & 15, lg = ln >> 4;

    f32x4 acc[2][4];
    #pragma unroll
    for (int a = 0; a < 2; a++)
        #pragma unroll
        for (int b = 0; b < 4; b++)
            acc[a][b] = (f32x4){0.f, 0.f, 0.f, 0.f};

    const short* As_h = Ah_s + (wr * 32 + lr) * APAD + lg * 8;
    const short* As_l = Al_s + (wr * 32 + lr) * APAD + lg * 8;

    #pragma unroll
    for (int ks = 0; ks < 4; ks++) {
        int ko = ks * 32;
        bf16x8 fa_h[2], fa_l[2], fb_h[4], fb_l[4];
        #pragma unroll
        for (int fr = 0; fr < 2; fr++) {
            fa_h[fr] = *(const bf16x8*)(As_h + fr * 16 * APAD + ko);
            fa_l[fr] = *(const bf16x8*)(As_l + fr * 16 * APAD + ko);
        }
        #pragma unroll
        for (int fc = 0; fc < 4; fc++) {
            int ccol = C0 + fc * 16 + lr;
            fb_h[fc] = *(const bf16x8*)(BhT + (size_t)ccol * D + ko + lg * 8);
            fb_l[fc] = *(const bf16x8*)(BlT + (size_t)ccol * D + ko + lg * 8);
        }
        #pragma unroll
        for (int fr = 0; fr < 2; fr++) {
            #pragma unroll
            for (int fc = 0; fc < 4; fc++) {
                acc[fr][fc] = __builtin_amdgcn_mfma_f32_16x16x32_bf16(
                    fa_h[fr], fb_h[fc], acc[fr][fc], 0, 0, 0);
                acc[fr][fc] = __builtin_amdgcn_mfma_f32_16x16x32_bf16(
                    fa_l[fr], fb_h[fc], acc[fr][fc], 0, 0, 0);
                acc[fr][fc] = __builtin_amdgcn_mfma_f32_16x16x32_bf16(
                    fa_h[fr], fb_l[fc], acc[fr][fc], 0, 0, 0);
            }
        }
    }
    gemm_store(acc, dinv, T_out, R0, C0, lr, lg);
}

// ---------------- final aggregation: fp32 out, no relu ----------------

__global__ __launch_bounds__(256) void k_agg_out(const __half* __restrict__ T,
                                                 const int* __restrict__ rowptr,
                                                 const int* __restrict__ col,
                                                 const float* __restrict__ dinv,
                                                 const float* __restrict__ bias,
                                                 float* __restrict__ Of) {
    int i = blockIdx.x * 8 + (threadIdx.x >> 5);
    int sl = threadIdx.x & 31;
    int f = sl * 4;
    float di = dinv[i];
    float2 raw = *(const float2*)(T + (size_t)i * D + f);
    __half2 s0 = *(__half2*)&raw.x, s1 = *(__half2*)&raw.y;
    float2 g0 = __half22float2(s0), g1 = __half22float2(s1);
    float a0 = g0.x, a1 = g0.y, a2 = g1.x, a3 = g1.y;

    int e = rowptr[i], r1 = rowptr[i + 1];
    for (; e + 8 <= r1; e += 8) {
        float2 rv[8];
        #pragma unroll
        for (int u = 0; u < 8; u++) {
            int s = col[e + u];
            rv[u] = *(const float2*)(T + (size_t)s * D + f);
        }
        #pragma unroll
        for (int u = 0; u < 8; u++) {
            __half2 x0 = *(__half2*)&rv[u].x, x1 = *(__half2*)&rv[u].y;
            float2 q0 = __half22float2(x0), q1 = __half22float2(x1);
            a0 += q0.x; a1 += q0.y; a2 += q1.x; a3 += q1.y;
        }
    }
    for (; e < r1; e++) {
        int s = col[e];
        float2 rv = *(const float2*)(T + (size_t)s * D + f);
        __half2 x0 = *(__half2*)&rv.x, x1 = *(__half2*)&rv.y;
        float2 q0 = __half22float2(x0), q1 = __half22float2(x1);
        a0 += q0.x; a1 += q0.y; a2 += q1.x; a3 += q1.y;
    }

    float4 bv = *(const float4*)(bias + f);
    *(float4*)(Of + (size_t)i * D + f) = make_float4(
        a0 * di + bv.x, a1 * di + bv.y, a2 * di + bv.z, a3 * di + bv.w);
}

// ---------------- launch ----------------

extern "C" void kernel_launch(void* const* d_in, const int* in_sizes, int n_in,
                              void* d_out, int out_size, void* d_ws, size_t ws_size,
                              hipStream_t stream) {
    const float* x  = (const float*)d_in[0];
    const int* edge = (const int*)d_in[1];
    const float* W0 = (const float*)d_in[2];
    const float* b0 = (const float*)d_in[3];
    const float* W1 = (const float*)d_in[4];
    const float* b1 = (const float*)d_in[5];
    const float* W2 = (const float*)d_in[6];
    const float* b2 = (const float*)d_in[7];
    const int* src = edge;
    const int* dst = edge + NE;
    float* out = (float*)d_out;

    char* ws = (char*)d_ws;
    size_t off = 0;
    auto alloc = [&](size_t bytes) {
        void* p = ws + off;
        off += (bytes + 255) & ~(size_t)255;
        return p;
    };
    int*   cnt    = (int*)alloc(NN * 4);
    int*   rowptr = (int*)alloc((NN + 1) * 4);
    float* dinv   = (float*)alloc(NN * 4);
    int*   bsum   = (int*)alloc(256 * 4);
    int*   boff   = (int*)alloc(256 * 4);
    int*   rank   = (int*)alloc((size_t)NE * 4);
    int*   col    = (int*)alloc((size_t)NE * 4);
    unsigned short* Wh = (unsigned short*)alloc(3 * D * D * 2);
    unsigned short* Wl = (unsigned short*)alloc(3 * D * D * 2);
    __half* Ta = (__half*)alloc((size_t)NPAD * D * 2);
    __half* Tb = (__half*)alloc((size_t)NPAD * D * 2);

    hipMemsetAsync(cnt, 0, NN * 4, stream);

    k_degree<<<(NE + 255) / 256, 256, 0, stream>>>(dst, cnt, rank);
    k_scan_block<<<(NN + 255) / 256, 256, 0, stream>>>(cnt, rowptr, bsum);
    k_scan_top<<<1, 256, 0, stream>>>(bsum, boff);
    k_scan_add<<<(NN + 256) / 256, 256, 0, stream>>>(rowptr, boff, cnt, dinv);
    k_fill<<<(NE + 255) / 256, 256, 0, stream>>>(src, dst, rowptr, rank, col);
    k_convW3<<<(3 * D * D + 255) / 256, 256, 0, stream>>>(W0, W1, W2, Wh, Wl);

    const int ggrid = (NN + 63) / 64;   // 782
    const int agrid = NN / 8;           // 6250

    // layer 0 GEMM: Ta = dinv * (x @ W0)
    k_gemm_mfma_x<<<ggrid, 256, 0, stream>>>(x, Wh, Wl, dinv, Ta);
    // fused: h1 = relu(agg(Ta)+b0); Tb = dinv * (h1 @ W1)
    k_agg_gemm<<<ggrid, 256, 0, stream>>>(Ta, rowptr, col, dinv, b0,
                                          Wh + D * D, Wl + D * D, Tb);
    // fused: h2 = relu(agg(Tb)+b1); Ta = dinv * (h2 @ W2)
    k_agg_gemm<<<ggrid, 256, 0, stream>>>(Tb, rowptr, col, dinv, b1,
                                          Wh + 2 * D * D, Wl + 2 * D * D, Ta);
    // final: out = dinv*(agg(Ta)) + b2
    k_agg_out<<<agrid, 256, 0, stream>>>(Ta, rowptr, col, dinv, b2, out);
}

// Round 7
// 243.628 us; speedup vs baseline: 1.0924x; 1.0924x over previous
//
#include <hip/hip_runtime.h>
#include <hip/hip_fp16.h>

#define NN 50000
#define NPAD 50048
#define NE 800000
#define D 128
#define BPAD 136

typedef __attribute__((ext_vector_type(8))) short bf16x8;
typedef __attribute__((ext_vector_type(4))) float f32x4;

__device__ inline unsigned short f2bf(float f) {
    unsigned int b = __float_as_uint(f);
    return (unsigned short)((b + 0x7FFFu + ((b >> 16) & 1u)) >> 16);
}
__device__ inline float bf2f(unsigned short u) {
    return __uint_as_float(((unsigned int)u) << 16);
}

// ---------------- CSR build ----------------

__global__ void k_degree(const int* __restrict__ dst, int* __restrict__ cnt,
                         int* __restrict__ rank) {
    int e = blockIdx.x * 256 + threadIdx.x;
    if (e < NE) {
        int d = dst[e];
        int r = atomicAdd(&cnt[d], 1);
        __builtin_nontemporal_store(r, &rank[e]);
    }
}

__global__ void k_scan_block(const int* __restrict__ cnt, int* __restrict__ excl,
                             int* __restrict__ bsum) {
    __shared__ int sm[256];
    int t = threadIdx.x;
    int idx = blockIdx.x * 256 + t;
    int v = (idx < NN) ? cnt[idx] : 0;
    sm[t] = v;
    __syncthreads();
    for (int o = 1; o < 256; o <<= 1) {
        int u = (t >= o) ? sm[t - o] : 0;
        __syncthreads();
        sm[t] += u;
        __syncthreads();
    }
    if (idx < NN) excl[idx] = sm[t] - v;
    if (t == 255) bsum[blockIdx.x] = sm[255];
}

__global__ void k_scan_top(const int* __restrict__ bsum, int* __restrict__ boff) {
    __shared__ int sm[256];
    const int NB = (NN + 255) / 256;
    int t = threadIdx.x;
    int v = (t < NB) ? bsum[t] : 0;
    sm[t] = v;
    __syncthreads();
    for (int o = 1; o < 256; o <<= 1) {
        int u = (t >= o) ? sm[t - o] : 0;
        __syncthreads();
        sm[t] += u;
        __syncthreads();
    }
    if (t < NB) boff[t] = sm[t] - v;
}

__global__ void k_scan_add(int* __restrict__ rowptr, const int* __restrict__ boff,
                           const int* __restrict__ cnt, float* __restrict__ dinv) {
    int idx = blockIdx.x * 256 + threadIdx.x;
    if (idx < NN) {
        rowptr[idx] += boff[idx >> 8];
        dinv[idx] = rsqrtf((float)(cnt[idx] + 1));
    } else if (idx == NN) {
        rowptr[NN] = NE;
    }
}

__global__ void k_fill(const int* __restrict__ src, const int* __restrict__ dst,
                       const int* __restrict__ rowptr, const int* __restrict__ rank,
                       int* __restrict__ col) {
    int e = blockIdx.x * 256 + threadIdx.x;
    if (e < NE) {
        int d = dst[e];
        int pos = rowptr[d] + rank[e];
        __builtin_nontemporal_store(src[e], &col[pos]);
    }
}

// ---------------- prep: W split-bf16 (transposed), all 3 ----------------

__global__ void k_convW3(const float* __restrict__ W0, const float* __restrict__ W1,
                         const float* __restrict__ W2, unsigned short* __restrict__ Wh,
                         unsigned short* __restrict__ Wl) {
    int i = blockIdx.x * 256 + threadIdx.x;
    if (i >= 3 * D * D) return;
    int m = i / (D * D), r = i - m * (D * D);
    const float* W = (m == 0) ? W0 : ((m == 1) ? W1 : W2);
    int k = r >> 7, c = r & 127;
    float v = W[r];
    unsigned short h = f2bf(v);
    unsigned short l = f2bf(v - bf2f(h));
    Wh[(size_t)m * D * D + c * D + k] = h;
    Wl[(size_t)m * D * D + c * D + k] = l;
}

// ---------------- GEMM epilogue ----------------

__device__ inline void gemm_store(f32x4 acc[2][4], const float* __restrict__ dinv,
                                  __half* __restrict__ C, int R0, int C0, int lr, int lg) {
    #pragma unroll
    for (int fr = 0; fr < 2; fr++) {
        int rb = R0 + fr * 16 + lg * 4;
        #pragma unroll
        for (int j = 0; j < 4; j++) {
            int r = rb + j;
            if (r < NN) {
                float s = dinv[r];
                #pragma unroll
                for (int fc = 0; fc < 4; fc++)
                    C[(size_t)r * D + C0 + fc * 16 + lr] =
                        __float2half_rn(acc[fr][fc][j] * s);
            }
        }
    }
}

// ---------------- layer 0 GEMM: fp32 X, split in-register ----------------

__global__ __launch_bounds__(256, 2) void k_gemm_mfma_x(
        const float* __restrict__ X,
        const unsigned short* __restrict__ BhT, const unsigned short* __restrict__ BlT,
        const float* __restrict__ dinv, __half* __restrict__ C) {
    __shared__ short Bs_h[D * BPAD];
    int t = threadIdx.x;
    {
        int c = t >> 1;
        int k0 = (t & 1) * 64;
        const unsigned short* gh = BhT + c * D + k0;
        short* dh = Bs_h + c * BPAD + k0;
        #pragma unroll
        for (int i = 0; i < 8; i++)
            *(int4*)(dh + i * 8) = *(const int4*)(gh + i * 8);
    }
    __syncthreads();

    int w = t >> 6, ln = t & 63;
    int wr = w >> 1, wc = w & 1;
    int R0 = blockIdx.x * 64 + wr * 32;
    int C0 = wc * 64;
    int lr = ln & 15, lg = ln >> 4;

    f32x4 acc[2][4];
    #pragma unroll
    for (int a = 0; a < 2; a++)
        #pragma unroll
        for (int b = 0; b < 4; b++)
            acc[a][b] = (f32x4){0.f, 0.f, 0.f, 0.f};

    const float* Ab = X + (size_t)(R0 + lr) * D + lg * 8;

    #pragma unroll
    for (int ks = 0; ks < 4; ks++) {
        int ko = ks * 32;
        bf16x8 fa_h[2], fa_l[2], fb_h[4], fb_l[4];
        #pragma unroll
        for (int fr = 0; fr < 2; fr++) {
            float4 p0 = *(const float4*)(Ab + fr * 16 * D + ko);
            float4 p1 = *(const float4*)(Ab + fr * 16 * D + ko + 4);
            float vv[8] = {p0.x, p0.y, p0.z, p0.w, p1.x, p1.y, p1.z, p1.w};
            #pragma unroll
            for (int j = 0; j < 8; j++) {
                unsigned short h = f2bf(vv[j]);
                fa_h[fr][j] = (short)h;
                fa_l[fr][j] = (short)f2bf(vv[j] - bf2f(h));
            }
        }
        #pragma unroll
        for (int fc = 0; fc < 4; fc++) {
            int ccol = C0 + fc * 16 + lr;
            fb_h[fc] = *(const bf16x8*)(Bs_h + ccol * BPAD + ko + lg * 8);
            fb_l[fc] = *(const bf16x8*)(BlT + (size_t)ccol * D + ko + lg * 8);
        }
        #pragma unroll
        for (int fr = 0; fr < 2; fr++) {
            #pragma unroll
            for (int fc = 0; fc < 4; fc++) {
                acc[fr][fc] = __builtin_amdgcn_mfma_f32_16x16x32_bf16(
                    fa_h[fr], fb_h[fc], acc[fr][fc], 0, 0, 0);
                acc[fr][fc] = __builtin_amdgcn_mfma_f32_16x16x32_bf16(
                    fa_l[fr], fb_h[fc], acc[fr][fc], 0, 0, 0);
                acc[fr][fc] = __builtin_amdgcn_mfma_f32_16x16x32_bf16(
                    fa_h[fr], fb_l[fc], acc[fr][fc], 0, 0, 0);
            }
        }
    }
    gemm_store(acc, dinv, C, R0, C0, lr, lg);
}

// ---------------- layers 1,2 GEMM: fp16 H, split in-register --------------
// fp16 (11-bit mantissa) splits losslessly into bf16 hi + bf16 lo.

__global__ __launch_bounds__(256, 3) void k_gemm_mfma_h(
        const __half* __restrict__ H,
        const unsigned short* __restrict__ BhT, const unsigned short* __restrict__ BlT,
        const float* __restrict__ dinv, __half* __restrict__ C) {
    __shared__ short Bs_h[D * BPAD];
    int t = threadIdx.x;
    {
        int c = t >> 1;
        int k0 = (t & 1) * 64;
        const unsigned short* gh = BhT + c * D + k0;
        short* dh = Bs_h + c * BPAD + k0;
        #pragma unroll
        for (int i = 0; i < 8; i++)
            *(int4*)(dh + i * 8) = *(const int4*)(gh + i * 8);
    }
    __syncthreads();

    int w = t >> 6, ln = t & 63;
    int wr = w >> 1, wc = w & 1;
    int R0 = blockIdx.x * 64 + wr * 32;
    int C0 = wc * 64;
    int lr = ln & 15, lg = ln >> 4;

    f32x4 acc[2][4];
    #pragma unroll
    for (int a = 0; a < 2; a++)
        #pragma unroll
        for (int b = 0; b < 4; b++)
            acc[a][b] = (f32x4){0.f, 0.f, 0.f, 0.f};

    const __half* Ab = H + (size_t)(R0 + lr) * D + lg * 8;

    #pragma unroll
    for (int ks = 0; ks < 4; ks++) {
        int ko = ks * 32;
        bf16x8 fa_h[2], fa_l[2], fb_h[4], fb_l[4];
        #pragma unroll
        for (int fr = 0; fr < 2; fr++) {
            float4 p = *(const float4*)(Ab + fr * 16 * D + ko);  // 8 halves
            const __half2* hp = (const __half2*)&p;
            #pragma unroll
            for (int q = 0; q < 4; q++) {
                float2 fv = __half22float2(hp[q]);
                unsigned short h0 = f2bf(fv.x), h1 = f2bf(fv.y);
                fa_h[fr][q * 2]     = (short)h0;
                fa_h[fr][q * 2 + 1] = (short)h1;
                fa_l[fr][q * 2]     = (short)f2bf(fv.x - bf2f(h0));
                fa_l[fr][q * 2 + 1] = (short)f2bf(fv.y - bf2f(h1));
            }
        }
        #pragma unroll
        for (int fc = 0; fc < 4; fc++) {
            int ccol = C0 + fc * 16 + lr;
            fb_h[fc] = *(const bf16x8*)(Bs_h + ccol * BPAD + ko + lg * 8);
            fb_l[fc] = *(const bf16x8*)(BlT + (size_t)ccol * D + ko + lg * 8);
        }
        #pragma unroll
        for (int fr = 0; fr < 2; fr++) {
            #pragma unroll
            for (int fc = 0; fc < 4; fc++) {
                acc[fr][fc] = __builtin_amdgcn_mfma_f32_16x16x32_bf16(
                    fa_h[fr], fb_h[fc], acc[fr][fc], 0, 0, 0);
                acc[fr][fc] = __builtin_amdgcn_mfma_f32_16x16x32_bf16(
                    fa_l[fr], fb_h[fc], acc[fr][fc], 0, 0, 0);
                acc[fr][fc] = __builtin_amdgcn_mfma_f32_16x16x32_bf16(
                    fa_h[fr], fb_l[fc], acc[fr][fc], 0, 0, 0);
            }
        }
    }
    gemm_store(acc, dinv, C, R0, C0, lr, lg);
}

// ---------------- Aggregation: 16 lanes/node, lane = 8 features ----------
// T fp16 pre-scaled by dinv[row]. h_out = relu(dinv[i]*(sum+self) + b), fp16.

__global__ __launch_bounds__(256) void k_agg_relu(const __half* __restrict__ T,
                                                  const int* __restrict__ rowptr,
                                                  const int* __restrict__ col,
                                                  const float* __restrict__ dinv,
                                                  const float* __restrict__ bias,
                                                  __half* __restrict__ Hout) {
    int i = blockIdx.x * 16 + (threadIdx.x >> 4);
    int sl = threadIdx.x & 15;
    int f = sl * 8;
    float di = dinv[i];
    float a[8];
    {
        float4 raw = *(const float4*)(T + (size_t)i * D + f);
        const __half2* hp = (const __half2*)&raw;
        #pragma unroll
        for (int q = 0; q < 4; q++) {
            float2 fv = __half22float2(hp[q]);
            a[q * 2] = fv.x;
            a[q * 2 + 1] = fv.y;
        }
    }
    int e = rowptr[i], r1 = rowptr[i + 1];
    for (; e + 8 <= r1; e += 8) {
        float4 rv[8];
        #pragma unroll
        for (int u = 0; u < 8; u++) {
            int s = col[e + u];
            rv[u] = *(const float4*)(T + (size_t)s * D + f);
        }
        #pragma unroll
        for (int u = 0; u < 8; u++) {
            const __half2* hp = (const __half2*)&rv[u];
            #pragma unroll
            for (int q = 0; q < 4; q++) {
                float2 fv = __half22float2(hp[q]);
                a[q * 2] += fv.x;
                a[q * 2 + 1] += fv.y;
            }
        }
    }
    for (; e < r1; e++) {
        int s = col[e];
        float4 rv = *(const float4*)(T + (size_t)s * D + f);
        const __half2* hp = (const __half2*)&rv;
        #pragma unroll
        for (int q = 0; q < 4; q++) {
            float2 fv = __half22float2(hp[q]);
            a[q * 2] += fv.x;
            a[q * 2 + 1] += fv.y;
        }
    }
    float4 bv0 = *(const float4*)(bias + f);
    float4 bv1 = *(const float4*)(bias + f + 4);
    float bb[8] = {bv0.x, bv0.y, bv0.z, bv0.w, bv1.x, bv1.y, bv1.z, bv1.w};
    __half2 o[4];
    #pragma unroll
    for (int q = 0; q < 4; q++) {
        float x0 = fmaxf(a[q * 2] * di + bb[q * 2], 0.f);
        float x1 = fmaxf(a[q * 2 + 1] * di + bb[q * 2 + 1], 0.f);
        o[q] = __floats2half2_rn(x0, x1);
    }
    *(float4*)(Hout + (size_t)i * D + f) = *(float4*)o;
}

// final layer: fp32 out, no relu
__global__ __launch_bounds__(256) void k_agg_out(const __half* __restrict__ T,
                                                 const int* __restrict__ rowptr,
                                                 const int* __restrict__ col,
                                                 const float* __restrict__ dinv,
                                                 const float* __restrict__ bias,
                                                 float* __restrict__ Of) {
    int i = blockIdx.x * 16 + (threadIdx.x >> 4);
    int sl = threadIdx.x & 15;
    int f = sl * 8;
    float di = dinv[i];
    float a[8];
    {
        float4 raw = *(const float4*)(T + (size_t)i * D + f);
        const __half2* hp = (const __half2*)&raw;
        #pragma unroll
        for (int q = 0; q < 4; q++) {
            float2 fv = __half22float2(hp[q]);
            a[q * 2] = fv.x;
            a[q * 2 + 1] = fv.y;
        }
    }
    int e = rowptr[i], r1 = rowptr[i + 1];
    for (; e + 8 <= r1; e += 8) {
        float4 rv[8];
        #pragma unroll
        for (int u = 0; u < 8; u++) {
            int s = col[e + u];
            rv[u] = *(const float4*)(T + (size_t)s * D + f);
        }
        #pragma unroll
        for (int u = 0; u < 8; u++) {
            const __half2* hp = (const __half2*)&rv[u];
            #pragma unroll
            for (int q = 0; q < 4; q++) {
                float2 fv = __half22float2(hp[q]);
                a[q * 2] += fv.x;
                a[q * 2 + 1] += fv.y;
            }
        }
    }
    for (; e < r1; e++) {
        int s = col[e];
        float4 rv = *(const float4*)(T + (size_t)s * D + f);
        const __half2* hp = (const __half2*)&rv;
        #pragma unroll
        for (int q = 0; q < 4; q++) {
            float2 fv = __half22float2(hp[q]);
            a[q * 2] += fv.x;
            a[q * 2 + 1] += fv.y;
        }
    }
    float4 bv0 = *(const float4*)(bias + f);
    float4 bv1 = *(const float4*)(bias + f + 4);
    float4 o0 = make_float4(a[0] * di + bv0.x, a[1] * di + bv0.y,
                            a[2] * di + bv0.z, a[3] * di + bv0.w);
    float4 o1 = make_float4(a[4] * di + bv1.x, a[5] * di + bv1.y,
                            a[6] * di + bv1.z, a[7] * di + bv1.w);
    *(float4*)(Of + (size_t)i * D + f) = o0;
    *(float4*)(Of + (size_t)i * D + f + 4) = o1;
}

// ---------------- launch ----------------

extern "C" void kernel_launch(void* const* d_in, const int* in_sizes, int n_in,
                              void* d_out, int out_size, void* d_ws, size_t ws_size,
                              hipStream_t stream) {
    const float* x  = (const float*)d_in[0];
    const int* edge = (const int*)d_in[1];
    const float* W0 = (const float*)d_in[2];
    const float* b0 = (const float*)d_in[3];
    const float* W1 = (const float*)d_in[4];
    const float* b1 = (const float*)d_in[5];
    const float* W2 = (const float*)d_in[6];
    const float* b2 = (const float*)d_in[7];
    const int* src = edge;
    const int* dst = edge + NE;
    float* out = (float*)d_out;

    char* ws = (char*)d_ws;
    size_t off = 0;
    auto alloc = [&](size_t bytes) {
        void* p = ws + off;
        off += (bytes + 255) & ~(size_t)255;
        return p;
    };
    int*   cnt    = (int*)alloc(NN * 4);
    int*   rowptr = (int*)alloc((NN + 1) * 4);
    float* dinv   = (float*)alloc(NN * 4);
    int*   bsum   = (int*)alloc(256 * 4);
    int*   boff   = (int*)alloc(256 * 4);
    int*   rank   = (int*)alloc((size_t)NE * 4);
    int*   col    = (int*)alloc((size_t)NE * 4);
    unsigned short* Wh = (unsigned short*)alloc(3 * D * D * 2);
    unsigned short* Wl = (unsigned short*)alloc(3 * D * D * 2);
    __half* Ta = (__half*)alloc((size_t)NPAD * D * 2);
    __half* Tb = (__half*)alloc((size_t)NPAD * D * 2);
    __half* Hb = (__half*)alloc((size_t)NPAD * D * 2);

    hipMemsetAsync(cnt, 0, NN * 4, stream);

    k_degree<<<(NE + 255) / 256, 256, 0, stream>>>(dst, cnt, rank);
    k_scan_block<<<(NN + 255) / 256, 256, 0, stream>>>(cnt, rowptr, bsum);
    k_scan_top<<<1, 256, 0, stream>>>(bsum, boff);
    k_scan_add<<<(NN + 256) / 256, 256, 0, stream>>>(rowptr, boff, cnt, dinv);
    k_fill<<<(NE + 255) / 256, 256, 0, stream>>>(src, dst, rowptr, rank, col);
    k_convW3<<<(3 * D * D + 255) / 256, 256, 0, stream>>>(W0, W1, W2, Wh, Wl);

    const int ggrid = (NN + 63) / 64;   // 782
    const int agrid = NN / 16;          // 3125

    // layer 0: Ta = dinv * (x @ W0)
    k_gemm_mfma_x<<<ggrid, 256, 0, stream>>>(x, Wh, Wl, dinv, Ta);
    // h1 = relu(agg(Ta)+b0)  [fp16]
    k_agg_relu<<<agrid, 256, 0, stream>>>(Ta, rowptr, col, dinv, b0, Hb);
    // Tb = dinv * (h1 @ W1)
    k_gemm_mfma_h<<<ggrid, 256, 0, stream>>>(Hb, Wh + D * D, Wl + D * D, dinv, Tb);
    // h2 = relu(agg(Tb)+b1)  [fp16]
    k_agg_relu<<<agrid, 256, 0, stream>>>(Tb, rowptr, col, dinv, b1, Hb);
    // Ta = dinv * (h2 @ W2)
    k_gemm_mfma_h<<<ggrid, 256, 0, stream>>>(Hb, Wh + 2 * D * D, Wl + 2 * D * D, dinv, Ta);
    // out = dinv*agg(Ta) + b2  [fp32]
    k_agg_out<<<agrid, 256, 0, stream>>>(Ta, rowptr, col, dinv, b2, out);
}

// Round 8
// 238.540 us; speedup vs baseline: 1.1157x; 1.0213x over previous
//
#include <hip/hip_runtime.h>
#include <hip/hip_fp16.h>

#define NN 50000
#define NPAD 50048
#define NE 800000
#define D 128
#define BPAD 136
#define EGRID 3125   // (NE+255)/256
#define NB 196       // (NN+255)/256

typedef __attribute__((ext_vector_type(8))) short bf16x8;
typedef __attribute__((ext_vector_type(4))) float f32x4;

__device__ inline unsigned short f2bf(float f) {
    unsigned int b = __float_as_uint(f);
    return (unsigned short)((b + 0x7FFFu + ((b >> 16) & 1u)) >> 16);
}
__device__ inline float bf2f(unsigned short u) {
    return __uint_as_float(((unsigned int)u) << 16);
}

// ---------------- CSR build + W conversion (fused role-split) ----------------

__global__ void k_degree_convW(const int* __restrict__ dst, int* __restrict__ cnt,
                               int* __restrict__ rank,
                               const float* __restrict__ W0, const float* __restrict__ W1,
                               const float* __restrict__ W2,
                               unsigned short* __restrict__ Wh, unsigned short* __restrict__ Wl) {
    int bid = blockIdx.x;
    int t = threadIdx.x;
    if (bid < EGRID) {
        int e = bid * 256 + t;
        if (e < NE) {
            int d = dst[e];
            int r = atomicAdd(&cnt[d], 1);
            __builtin_nontemporal_store(r, &rank[e]);
        }
    } else {
        int i = (bid - EGRID) * 256 + t;
        if (i >= 3 * D * D) return;
        int m = i / (D * D), r = i - m * (D * D);
        const float* W = (m == 0) ? W0 : ((m == 1) ? W1 : W2);
        int k = r >> 7, c = r & 127;
        float v = W[r];
        unsigned short h = f2bf(v);
        unsigned short l = f2bf(v - bf2f(h));
        Wh[(size_t)m * D * D + c * D + k] = h;
        Wl[(size_t)m * D * D + c * D + k] = l;
    }
}

// block scan + (last block) top scan, via ticket
__global__ void k_scan_block(const int* __restrict__ cnt, int* __restrict__ excl,
                             int* __restrict__ bsum, int* __restrict__ boff,
                             int* __restrict__ counter) {
    __shared__ int sm[256];
    __shared__ int lastflag;
    int t = threadIdx.x;
    int idx = blockIdx.x * 256 + t;
    int v = (idx < NN) ? cnt[idx] : 0;
    sm[t] = v;
    __syncthreads();
    for (int o = 1; o < 256; o <<= 1) {
        int u = (t >= o) ? sm[t - o] : 0;
        __syncthreads();
        sm[t] += u;
        __syncthreads();
    }
    if (idx < NN) excl[idx] = sm[t] - v;
    if (t == 255) bsum[blockIdx.x] = sm[255];
    __threadfence();
    if (t == 0) {
        int ticket = atomicAdd(counter, 1);
        lastflag = (ticket == NB - 1);
    }
    __syncthreads();
    if (!lastflag) return;
    __threadfence();  // acquire: all blocks' bsum visible
    int v2 = (t < NB) ? bsum[t] : 0;
    sm[t] = v2;
    __syncthreads();
    for (int o = 1; o < 256; o <<= 1) {
        int u = (t >= o) ? sm[t - o] : 0;
        __syncthreads();
        sm[t] += u;
        __syncthreads();
    }
    if (t < NB) boff[t] = sm[t] - v2;
}

__global__ void k_scan_add(int* __restrict__ rowptr, const int* __restrict__ boff,
                           const int* __restrict__ cnt, float* __restrict__ dinv) {
    int idx = blockIdx.x * 256 + threadIdx.x;
    if (idx < NN) {
        rowptr[idx] += boff[idx >> 8];
        dinv[idx] = rsqrtf((float)(cnt[idx] + 1));
    } else if (idx == NN) {
        rowptr[NN] = NE;
    }
}

__global__ void k_fill(const int* __restrict__ src, const int* __restrict__ dst,
                       const int* __restrict__ rowptr, const int* __restrict__ rank,
                       int* __restrict__ col) {
    int e = blockIdx.x * 256 + threadIdx.x;
    if (e < NE) {
        int d = dst[e];
        int pos = rowptr[d] + rank[e];
        __builtin_nontemporal_store(src[e], &col[pos]);
    }
}

// ---------------- GEMM epilogue ----------------

__device__ inline void gemm_store(f32x4 acc[2][4], const float* __restrict__ dinv,
                                  __half* __restrict__ C, int R0, int C0, int lr, int lg) {
    #pragma unroll
    for (int fr = 0; fr < 2; fr++) {
        int rb = R0 + fr * 16 + lg * 4;
        #pragma unroll
        for (int j = 0; j < 4; j++) {
            int r = rb + j;
            if (r < NN) {
                float s = dinv[r];
                #pragma unroll
                for (int fc = 0; fc < 4; fc++)
                    C[(size_t)r * D + C0 + fc * 16 + lr] =
                        __float2half_rn(acc[fr][fc][j] * s);
            }
        }
    }
}

// ---------------- layer 0 GEMM: fp32 X, split in-register ----------------

__global__ __launch_bounds__(256, 2) void k_gemm_mfma_x(
        const float* __restrict__ X,
        const unsigned short* __restrict__ BhT, const unsigned short* __restrict__ BlT,
        const float* __restrict__ dinv, __half* __restrict__ C) {
    __shared__ short Bs_h[D * BPAD];
    int t = threadIdx.x;
    {
        int c = t >> 1;
        int k0 = (t & 1) * 64;
        const unsigned short* gh = BhT + c * D + k0;
        short* dh = Bs_h + c * BPAD + k0;
        #pragma unroll
        for (int i = 0; i < 8; i++)
            *(int4*)(dh + i * 8) = *(const int4*)(gh + i * 8);
    }
    __syncthreads();

    int w = t >> 6, ln = t & 63;
    int wr = w >> 1, wc = w & 1;
    int R0 = blockIdx.x * 64 + wr * 32;
    int C0 = wc * 64;
    int lr = ln & 15, lg = ln >> 4;

    f32x4 acc[2][4];
    #pragma unroll
    for (int a = 0; a < 2; a++)
        #pragma unroll
        for (int b = 0; b < 4; b++)
            acc[a][b] = (f32x4){0.f, 0.f, 0.f, 0.f};

    const float* Ab = X + (size_t)(R0 + lr) * D + lg * 8;

    #pragma unroll
    for (int ks = 0; ks < 4; ks++) {
        int ko = ks * 32;
        bf16x8 fa_h[2], fa_l[2], fb_h[4], fb_l[4];
        #pragma unroll
        for (int fr = 0; fr < 2; fr++) {
            float4 p0 = *(const float4*)(Ab + fr * 16 * D + ko);
            float4 p1 = *(const float4*)(Ab + fr * 16 * D + ko + 4);
            float vv[8] = {p0.x, p0.y, p0.z, p0.w, p1.x, p1.y, p1.z, p1.w};
            #pragma unroll
            for (int j = 0; j < 8; j++) {
                unsigned short h = f2bf(vv[j]);
                fa_h[fr][j] = (short)h;
                fa_l[fr][j] = (short)f2bf(vv[j] - bf2f(h));
            }
        }
        #pragma unroll
        for (int fc = 0; fc < 4; fc++) {
            int ccol = C0 + fc * 16 + lr;
            fb_h[fc] = *(const bf16x8*)(Bs_h + ccol * BPAD + ko + lg * 8);
            fb_l[fc] = *(const bf16x8*)(BlT + (size_t)ccol * D + ko + lg * 8);
        }
        #pragma unroll
        for (int fr = 0; fr < 2; fr++) {
            #pragma unroll
            for (int fc = 0; fc < 4; fc++) {
                acc[fr][fc] = __builtin_amdgcn_mfma_f32_16x16x32_bf16(
                    fa_h[fr], fb_h[fc], acc[fr][fc], 0, 0, 0);
                acc[fr][fc] = __builtin_amdgcn_mfma_f32_16x16x32_bf16(
                    fa_l[fr], fb_h[fc], acc[fr][fc], 0, 0, 0);
                acc[fr][fc] = __builtin_amdgcn_mfma_f32_16x16x32_bf16(
                    fa_h[fr], fb_l[fc], acc[fr][fc], 0, 0, 0);
            }
        }
    }
    gemm_store(acc, dinv, C, R0, C0, lr, lg);
}

// ---------------- layers 1,2 GEMM: fp16 H, split in-register --------------

__global__ __launch_bounds__(256, 3) void k_gemm_mfma_h(
        const __half* __restrict__ H,
        const unsigned short* __restrict__ BhT, const unsigned short* __restrict__ BlT,
        const float* __restrict__ dinv, __half* __restrict__ C) {
    __shared__ short Bs_h[D * BPAD];
    int t = threadIdx.x;
    {
        int c = t >> 1;
        int k0 = (t & 1) * 64;
        const unsigned short* gh = BhT + c * D + k0;
        short* dh = Bs_h + c * BPAD + k0;
        #pragma unroll
        for (int i = 0; i < 8; i++)
            *(int4*)(dh + i * 8) = *(const int4*)(gh + i * 8);
    }
    __syncthreads();

    int w = t >> 6, ln = t & 63;
    int wr = w >> 1, wc = w & 1;
    int R0 = blockIdx.x * 64 + wr * 32;
    int C0 = wc * 64;
    int lr = ln & 15, lg = ln >> 4;

    f32x4 acc[2][4];
    #pragma unroll
    for (int a = 0; a < 2; a++)
        #pragma unroll
        for (int b = 0; b < 4; b++)
            acc[a][b] = (f32x4){0.f, 0.f, 0.f, 0.f};

    const __half* Ab = H + (size_t)(R0 + lr) * D + lg * 8;

    #pragma unroll
    for (int ks = 0; ks < 4; ks++) {
        int ko = ks * 32;
        bf16x8 fa_h[2], fa_l[2], fb_h[4], fb_l[4];
        #pragma unroll
        for (int fr = 0; fr < 2; fr++) {
            float4 p = *(const float4*)(Ab + fr * 16 * D + ko);
            const __half2* hp = (const __half2*)&p;
            #pragma unroll
            for (int q = 0; q < 4; q++) {
                float2 fv = __half22float2(hp[q]);
                unsigned short h0 = f2bf(fv.x), h1 = f2bf(fv.y);
                fa_h[fr][q * 2]     = (short)h0;
                fa_h[fr][q * 2 + 1] = (short)h1;
                fa_l[fr][q * 2]     = (short)f2bf(fv.x - bf2f(h0));
                fa_l[fr][q * 2 + 1] = (short)f2bf(fv.y - bf2f(h1));
            }
        }
        #pragma unroll
        for (int fc = 0; fc < 4; fc++) {
            int ccol = C0 + fc * 16 + lr;
            fb_h[fc] = *(const bf16x8*)(Bs_h + ccol * BPAD + ko + lg * 8);
            fb_l[fc] = *(const bf16x8*)(BlT + (size_t)ccol * D + ko + lg * 8);
        }
        #pragma unroll
        for (int fr = 0; fr < 2; fr++) {
            #pragma unroll
            for (int fc = 0; fc < 4; fc++) {
                acc[fr][fc] = __builtin_amdgcn_mfma_f32_16x16x32_bf16(
                    fa_h[fr], fb_h[fc], acc[fr][fc], 0, 0, 0);
                acc[fr][fc] = __builtin_amdgcn_mfma_f32_16x16x32_bf16(
                    fa_l[fr], fb_h[fc], acc[fr][fc], 0, 0, 0);
                acc[fr][fc] = __builtin_amdgcn_mfma_f32_16x16x32_bf16(
                    fa_h[fr], fb_l[fc], acc[fr][fc], 0, 0, 0);
            }
        }
    }
    gemm_store(acc, dinv, C, R0, C0, lr, lg);
}

// ---------------- Aggregation: 16 lanes/node, coalesced col + shfl --------
// Per 8-edge chunk: lane (sl&7) loads col[e+(sl&7)] coalesced (1 VMEM instr),
// indices broadcast via __shfl, 8 gathers kept in flight; junk slots (u>=m)
// clamp to the last edge -> same-address loads, L1-merged; accumulate predicated.

__device__ inline void agg_accum(const float4& rv, float a[8]) {
    const __half2* hp = (const __half2*)&rv;
    #pragma unroll
    for (int q = 0; q < 4; q++) {
        float2 fv = __half22float2(hp[q]);
        a[q * 2] += fv.x;
        a[q * 2 + 1] += fv.y;
    }
}

__device__ inline void agg_core(const __half* __restrict__ T,
                                const int* __restrict__ rowptr,
                                const int* __restrict__ col,
                                int i, int f, int lane, float a[8]) {
    int gb = lane & 48;
    int sl8 = lane & 7;
    {
        float4 raw = *(const float4*)(T + (size_t)i * D + f);
        const __half2* hp = (const __half2*)&raw;
        #pragma unroll
        for (int q = 0; q < 4; q++) {
            float2 fv = __half22float2(hp[q]);
            a[q * 2] = fv.x;
            a[q * 2 + 1] = fv.y;
        }
    }
    int r0 = rowptr[i], r1 = rowptr[i + 1];
    for (int e = r0; e < r1; e += 8) {
        int idx = e + sl8;
        if (idx > r1 - 1) idx = r1 - 1;
        int cv = col[idx];
        int m = r1 - e;
        m = m > 8 ? 8 : m;
        int ss[8];
        #pragma unroll
        for (int u = 0; u < 8; u++) ss[u] = __shfl(cv, gb + u, 64);
        float4 rv[8];
        #pragma unroll
        for (int u = 0; u < 8; u++)
            rv[u] = *(const float4*)(T + (size_t)ss[u] * D + f);
        #pragma unroll
        for (int u = 0; u < 8; u++)
            if (u < m) agg_accum(rv[u], a);
    }
}

__global__ __launch_bounds__(256) void k_agg_relu(const __half* __restrict__ T,
                                                  const int* __restrict__ rowptr,
                                                  const int* __restrict__ col,
                                                  const float* __restrict__ dinv,
                                                  const float* __restrict__ bias,
                                                  __half* __restrict__ Hout) {
    int i = blockIdx.x * 16 + (threadIdx.x >> 4);
    int lane = threadIdx.x & 63;
    int sl = threadIdx.x & 15;
    int f = sl * 8;
    float di = dinv[i];
    float a[8];
    agg_core(T, rowptr, col, i, f, lane, a);
    float4 bv0 = *(const float4*)(bias + f);
    float4 bv1 = *(const float4*)(bias + f + 4);
    float bb[8] = {bv0.x, bv0.y, bv0.z, bv0.w, bv1.x, bv1.y, bv1.z, bv1.w};
    __half2 o[4];
    #pragma unroll
    for (int q = 0; q < 4; q++) {
        float x0 = fmaxf(a[q * 2] * di + bb[q * 2], 0.f);
        float x1 = fmaxf(a[q * 2 + 1] * di + bb[q * 2 + 1], 0.f);
        o[q] = __floats2half2_rn(x0, x1);
    }
    *(float4*)(Hout + (size_t)i * D + f) = *(float4*)o;
}

__global__ __launch_bounds__(256) void k_agg_out(const __half* __restrict__ T,
                                                 const int* __restrict__ rowptr,
                                                 const int* __restrict__ col,
                                                 const float* __restrict__ dinv,
                                                 const float* __restrict__ bias,
                                                 float* __restrict__ Of) {
    int i = blockIdx.x * 16 + (threadIdx.x >> 4);
    int lane = threadIdx.x & 63;
    int sl = threadIdx.x & 15;
    int f = sl * 8;
    float di = dinv[i];
    float a[8];
    agg_core(T, rowptr, col, i, f, lane, a);
    float4 bv0 = *(const float4*)(bias + f);
    float4 bv1 = *(const float4*)(bias + f + 4);
    float4 o0 = make_float4(a[0] * di + bv0.x, a[1] * di + bv0.y,
                            a[2] * di + bv0.z, a[3] * di + bv0.w);
    float4 o1 = make_float4(a[4] * di + bv1.x, a[5] * di + bv1.y,
                            a[6] * di + bv1.z, a[7] * di + bv1.w);
    *(float4*)(Of + (size_t)i * D + f) = o0;
    *(float4*)(Of + (size_t)i * D + f + 4) = o1;
}

// ---------------- launch ----------------

extern "C" void kernel_launch(void* const* d_in, const int* in_sizes, int n_in,
                              void* d_out, int out_size, void* d_ws, size_t ws_size,
                              hipStream_t stream) {
    const float* x  = (const float*)d_in[0];
    const int* edge = (const int*)d_in[1];
    const float* W0 = (const float*)d_in[2];
    const float* b0 = (const float*)d_in[3];
    const float* W1 = (const float*)d_in[4];
    const float* b1 = (const float*)d_in[5];
    const float* W2 = (const float*)d_in[6];
    const float* b2 = (const float*)d_in[7];
    const int* src = edge;
    const int* dst = edge + NE;
    float* out = (float*)d_out;

    char* ws = (char*)d_ws;
    size_t off = 0;
    auto alloc = [&](size_t bytes) {
        void* p = ws + off;
        off += (bytes + 255) & ~(size_t)255;
        return p;
    };
    int*   cnt     = (int*)alloc(NN * 4);
    int*   counter = (int*)alloc(256);
    int*   rowptr  = (int*)alloc((NN + 1) * 4);
    float* dinv    = (float*)alloc(NN * 4);
    int*   bsum    = (int*)alloc(256 * 4);
    int*   boff    = (int*)alloc(256 * 4);
    int*   rank    = (int*)alloc((size_t)NE * 4);
    int*   col     = (int*)alloc((size_t)NE * 4);
    unsigned short* Wh = (unsigned short*)alloc(3 * D * D * 2);
    unsigned short* Wl = (unsigned short*)alloc(3 * D * D * 2);
    __half* Ta = (__half*)alloc((size_t)NPAD * D * 2);
    __half* Tb = (__half*)alloc((size_t)NPAD * D * 2);
    __half* Hb = (__half*)alloc((size_t)NPAD * D * 2);

    hipMemsetAsync(cnt, 0, NN * 4, stream);
    hipMemsetAsync(counter, 0, 256, stream);

    k_degree_convW<<<EGRID + 192, 256, 0, stream>>>(dst, cnt, rank, W0, W1, W2, Wh, Wl);
    k_scan_block<<<NB, 256, 0, stream>>>(cnt, rowptr, bsum, boff, counter);
    k_scan_add<<<(NN + 256) / 256, 256, 0, stream>>>(rowptr, boff, cnt, dinv);
    k_fill<<<EGRID, 256, 0, stream>>>(src, dst, rowptr, rank, col);

    const int ggrid = (NN + 63) / 64;   // 782
    const int agrid = NN / 16;          // 3125

    // layer 0: Ta = dinv * (x @ W0)
    k_gemm_mfma_x<<<ggrid, 256, 0, stream>>>(x, Wh, Wl, dinv, Ta);
    // h1 = relu(agg(Ta)+b0)  [fp16]
    k_agg_relu<<<agrid, 256, 0, stream>>>(Ta, rowptr, col, dinv, b0, Hb);
    // Tb = dinv * (h1 @ W1)
    k_gemm_mfma_h<<<ggrid, 256, 0, stream>>>(Hb, Wh + D * D, Wl + D * D, dinv, Tb);
    // h2 = relu(agg(Tb)+b1)  [fp16]
    k_agg_relu<<<agrid, 256, 0, stream>>>(Tb, rowptr, col, dinv, b1, Hb);
    // Ta = dinv * (h2 @ W2)
    k_gemm_mfma_h<<<ggrid, 256, 0, stream>>>(Hb, Wh + 2 * D * D, Wl + 2 * D * D, dinv, Ta);
    // out = dinv*agg(Ta) + b2  [fp32]
    k_agg_out<<<agrid, 256, 0, stream>>>(Ta, rowptr, col, dinv, b2, out);
}